// Round 16
// baseline (186.653 us; speedup 1.0000x reference)
//
#include <hip/hip_runtime.h>

#define DIM 16
#define HID 256
#define NSTEPS 10
#define TILE_B 16
#define NTHR 512
#define LSH 264      // bf16 LDS row stride (shorts) for w3t; fp8 tiles use 264-BYTE stride.
                     // R30 (resubmit; prior run died on container infra, kernel unmeasured).
                     // 2 BLOCKS/CU OVERLAP. R27/R29 plateaued at 127us with 86% combined
                     // issue -- the rest is cross-barrier bubbles (10/16 waves idle in B4->B1).
                     // TILE_B=16, 512 thr (8 waves), grid=512 -> exactly 2 blocks/CU (LDS
                     // ~49.3KB/block, VGPR ~120<=128 @ 4 waves/SIMD): block A's serial phases
                     // overlap block B's P1/P2. Waves are now SYMMETRIC (each computes both
                     // W2@h1 -> h2 and M@d1 -> v for its 32-col n-block; breg 32->64 regs).
                     // Bonus: d2 and v for the same (n,b) are now in the SAME LANE -> divergence
                     // dot is register-local fma; the d2f8 tile + all its LDS traffic + fp8
                     // decode are DELETED (dot is also more accurate: raw f32 d2).

typedef __attribute__((ext_vector_type(8))) short bf16x8;
typedef __attribute__((ext_vector_type(4))) short bf16x4;
typedef __attribute__((ext_vector_type(4))) float f32x4;
typedef __attribute__((ext_vector_type(2))) float f32x2;
typedef __attribute__((ext_vector_type(2))) unsigned int u32x2;

__device__ __forceinline__ unsigned short f2bf(float f) {
    unsigned u = __float_as_uint(f);
    u += 0x7fff + ((u >> 16) & 1);          // RNE
    return (unsigned short)(u >> 16);
}
__device__ __forceinline__ unsigned cvt_pk_bf16(float lo, float hi) {   // [bf16(hi):bf16(lo)], RNE
    unsigned r;
    asm("v_cvt_pk_bf16_f32 %0, %1, %2" : "=v"(r) : "v"(lo), "v"(hi));
    return r;
}
__device__ __forceinline__ unsigned packtr(float a, float b) {   // [bf16(b):bf16(a)], trunc
    return __builtin_amdgcn_perm(__float_as_uint(b), __float_as_uint(a), 0x07060302u);
}
__device__ __forceinline__ unsigned pk4_fp8(float a, float b, float c, float d) {
    int w = __builtin_amdgcn_cvt_pk_fp8_f32(a, b, 0, false);     // bytes 0,1
    w = __builtin_amdgcn_cvt_pk_fp8_f32(c, d, w, true);          // bytes 2,3
    return (unsigned)w;
}
__device__ __forceinline__ void silu_both(float x, float& h, float& d) {
    float s = __builtin_amdgcn_rcpf(1.0f + __expf(-x));
    h = x * s;
    d = fmaf(h, 1.0f - s, s);               // silu' = s + h*(1-s)
}

#if defined(__has_builtin) && __has_builtin(__builtin_amdgcn_mfma_f32_16x16x16bf16_1k)
__device__ __forceinline__ f32x4 mfma16(bf16x4 a, bf16x4 b, f32x4 c) {
    return __builtin_amdgcn_mfma_f32_16x16x16bf16_1k(a, b, c, 0, 0, 0);
}
#else
__device__ __forceinline__ f32x4 mfma16(bf16x4 a, bf16x4 b, f32x4 c) {
    asm volatile("s_nop 1\n\t"
                 "v_mfma_f32_16x16x16_bf16 %0, %1, %2, %0\n\t"
                 "s_nop 7\n\t"
                 "s_nop 7"
                 : "+v"(c) : "v"(a), "v"(b));
    return c;
}
#endif

// w2f8[n][j] = fp8(W2[j][n]);  mtf8[n][j] = fp8(M[j][n]), M[j][n] = W2[j][n]*sum_i W1[i][j]*W3[n][i]
__global__ void cnf_setup(const float* __restrict__ W1, const float* __restrict__ W2,
                          const float* __restrict__ W3,
                          unsigned char* __restrict__ w2f8, unsigned char* __restrict__ mtf8) {
    const int n = blockIdx.x;
    const int j = threadIdx.x;
    float g = 0.0f;
#pragma unroll
    for (int i = 0; i < DIM; ++i) g = fmaf(W1[i * HID + j], W3[n * DIM + i], g);
    const float w2 = W2[j * HID + n];
    w2f8[n * HID + j] = (unsigned char)(__builtin_amdgcn_cvt_pk_fp8_f32(w2, w2, 0, false) & 0xff);
    const float m = w2 * g;
    mtf8[n * HID + j] = (unsigned char)(__builtin_amdgcn_cvt_pk_fp8_f32(m, m, 0, false) & 0xff);
}

__global__ __launch_bounds__(NTHR, 4) void cnf_main(
    const float* __restrict__ x,
    const float* __restrict__ W1, const float* __restrict__ b1,
    const float* __restrict__ b2, const float* __restrict__ b3,
    const unsigned char* __restrict__ w2f8, const unsigned char* __restrict__ mtf8,
    const float* __restrict__ W3, float* __restrict__ out)
{
    __shared__ unsigned short zb[TILE_B][40];   // z-ext^T rows b=0..15: cols 0..15=z, 16=t, 17=1, rest 0
                                                // physical col = logical col ^ (8*bit3(r)) [2-way free]
    __shared__ unsigned short w1e[HID][40];     // W1ext^T rows n, cols k=0..31 (16=t-row, 17=b1, rest 0)
    __shared__ unsigned short w3t[DIM][LSH];    // w3t[i][n] = W3[n][i]
    __shared__ unsigned char  h1f8[TILE_B][264];// fp8 h1 [b][n], 264-B stride
    __shared__ unsigned char  d1f8[TILE_B][264];
    __shared__ alignas(16) float fzp[8][TILE_B][20];  // fz partials [wave][b][i], stride 20
    __shared__ alignas(16) float divp[8][TILE_B];
    __shared__ alignas(16) float b2l[HID];
    __shared__ alignas(16) float b3l[DIM];

    const int tid  = (int)threadIdx.x;
    const int lane = tid & 63;
    const int wv   = tid >> 6;            // 0..7
    const int g    = lane >> 4;           // quad 0..3
    const int r    = lane & 15;
    const int g8   = g * 8;
    const int b0   = (int)blockIdx.x * TILE_B;
    const int zsw  = ((r >> 3) & 1) << 3; // zb swizzle (8-short granule)
    const int n0w  = wv * 32;             // this wave's 32-col n-block

    // ---- z-state: wave 0, lane (r,g) holds z[b=r][i=4g+q], fp32 ----
    float zb4[4] = {0, 0, 0, 0}, za4[4] = {0, 0, 0, 0};
    if (wv == 0) {
        const f32x4 xv = *(const f32x4*)&x[(b0 + r) * DIM + 4 * g];
#pragma unroll
        for (int q = 0; q < 4; ++q) zb4[q] = xv[q];
        u32x2 pz = { cvt_pk_bf16(zb4[0], zb4[1]), cvt_pk_bf16(zb4[2], zb4[3]) };
        *(u32x2*)&zb[r][(4 * g) ^ zsw] = pz;
    }
    if (tid < TILE_B) {      // ext cols: t(=0 for stage 0), one, zeros
        const int zswi = ((tid >> 3) & 1) << 3;
#pragma unroll
        for (int c = 16; c < 32; ++c)
            zb[tid][c ^ zswi] = (c == 17) ? (unsigned short)0x3F80 : (unsigned short)0;
    }
    {                        // w1e[n][k]: W1ext^T (one-time build, 512 threads x 16 entries)
        const int n = tid >> 1, kh = (tid & 1) * 16;
#pragma unroll
        for (int e = 0; e < 16; ++e) {
            const int k = kh + e;
            float v = 0.0f;
            if (k < 17)       v = W1[k * HID + n];   // k=16 is the t-row of W1
            else if (k == 17) v = b1[n];
            w1e[n][k] = f2bf(v);
        }
    }
    {                        // w3t[i][n] = W3[n][i] (512 threads)
        const int n = tid >> 5, k0 = (tid & 31) * 8;
#pragma unroll
        for (int j = 0; j < 8; ++j) w3t[n][k0 + j] = f2bf(W3[(k0 + j) * DIM + n]);
    }
    if (tid < HID) b2l[tid] = b2[tid];   // biases live in LDS, re-read per stage
    if (tid < DIM) b3l[tid] = b3[tid];

    __syncthreads();         // init tables ready: hoist loop-invariant fragments
    const bf16x8 w1v0 = *(const bf16x8*)&w1e[n0w + r][g8];
    const bf16x8 w1v1 = *(const bf16x8*)&w1e[n0w + 16 + r][g8];
    const bf16x4 w3f0 = *(const bf16x4*)&w3t[r][n0w + 4 * g];
    const bf16x4 w3f1 = *(const bf16x4*)&w3t[r][n0w + 16 + 4 * g];

    // ---- phase-2 operand fragments: W2^T AND M^T rows for this wave's n-block (fp8, 64 regs) ----
    long long bw2[8][2], bmt[8][2];
    {
#pragma unroll
        for (int k = 0; k < 8; ++k)
#pragma unroll
            for (int nt = 0; nt < 2; ++nt) {
                const int off = (n0w + nt * 16 + r) * HID + k * 32 + g8;
                bw2[k][nt] = *(const long long*)(w2f8 + off);
                bmt[k][nt] = *(const long long*)(mtf8 + off);
            }
    }

    float lacc = 0.0f, logp = 0.0f;
    const float dt = 0.1f, dt6 = dt / 6.0f;

    for (int it = 0; it < NSTEPS * 4; ++it) {
        const int s = it & 3;
        const float wst = (s == 1 || s == 2) ? 2.0f : 1.0f;
        int opq = 0;
        asm volatile("" : "+v"(opq));    // opaque 0: blocks hoisting of per-stage bias reloads
        __syncthreads();   // B1: zb (z + t col), prev-stage divp/fzp ready

        // ---------- deferred logp update for the PREVIOUS stage (wave 1) ----------
        if (wv == 1 && lane < TILE_B && it) {
            const int ps = (it + 3) & 3;
            const float pw = (ps == 1 || ps == 2) ? 2.0f : 1.0f;
            float dv = 0.0f;
#pragma unroll
            for (int w = 0; w < 8; ++w) dv += divp[w][lane];
            lacc = fmaf(-pw, dv, lacc);
            if (ps == 3) { logp = fmaf(dt6, lacc, logp); lacc = 0.0f; }
        }

        // ---------- phase 1 (all 8 waves): pre1^T[n][b] = W1ext^T @ zext^T for the wave's
        //            32 n-cols -> h1,d1 fp8, single b32 store each ----------
        {
            const bf16x8 bz = *(const bf16x8*)&zb[r][g8 ^ zsw];
#pragma unroll
            for (int nt = 0; nt < 2; ++nt) {
                f32x4 c = {0.f, 0.f, 0.f, 0.f};
                c = __builtin_amdgcn_mfma_f32_16x16x32_bf16(nt ? w1v1 : w1v0, bz, c, 0, 0, 0);
                float h[4], d[4];
#pragma unroll
                for (int q = 0; q < 4; ++q) silu_both(c[q], h[q], d[q]);
                const int col = n0w + nt * 16 + 4 * g;     // byte col, dword-aligned
                *(unsigned*)&h1f8[r][col] = pk4_fp8(h[0], h[1], h[2], h[3]);
                *(unsigned*)&d1f8[r][col] = pk4_fp8(d[0], d[1], d[2], d[3]);
            }
        }
        __syncthreads();   // B2: h1/d1 ready

        // ---------- phase 2 (symmetric): each wave computes BOTH h2-pre (W2^T@h1^T) and
        //            v (M^T@d1^T) for its n-block. C[n][b], batch in lanes ----------
        f32x4 ch[2], cv[2];    // [nt]; ch[nt][q] = pre2[n0w+nt*16+4g+q][b=r], cv = v[...]
        {
#pragma unroll
            for (int nt = 0; nt < 2; ++nt) {
                ch[nt] = (f32x4){0.f, 0.f, 0.f, 0.f};
                cv[nt] = (f32x4){0.f, 0.f, 0.f, 0.f};
            }
            __builtin_amdgcn_s_setprio(1);
#pragma unroll
            for (int k = 0; k < 8; ++k) {
                const long long afh = *(const long long*)&h1f8[r][k * 32 + g8];
                const long long afd = *(const long long*)&d1f8[r][k * 32 + g8];
#pragma unroll
                for (int nt = 0; nt < 2; ++nt) {
                    ch[nt] = __builtin_amdgcn_mfma_f32_16x16x32_fp8_fp8(bw2[k][nt], afh, ch[nt], 0, 0, 0);
                    cv[nt] = __builtin_amdgcn_mfma_f32_16x16x32_fp8_fp8(bmt[k][nt], afd, cv[nt], 0, 0, 0);
                }
            }
            __builtin_amdgcn_s_setprio(0);
        }
        // ---------- epilogue (all waves, register-local): silu -> h2 (bf16 regs) -> fz
        //            partial via K=16 MFMA; divergence dot d2.*v with NO LDS round-trip ----------
        {
            const f32x4* bp20 = (const f32x4*)&b2l[n0w + 4 * g];
            const f32x4* bp21 = (const f32x4*)&b2l[n0w + 16 + 4 * g];
            const f32x4 bb0 = bp20[opq], bb1 = bp21[opq];   // per-stage reload, not registers
            f32x4 cp = {0.f, 0.f, 0.f, 0.f};
            float pp = 0.0f;
#pragma unroll
            for (int nt = 0; nt < 2; ++nt) {
                const f32x4 bb = nt ? bb1 : bb0;
                float h[4], d[4];
#pragma unroll
                for (int q = 0; q < 4; ++q) silu_both(ch[nt][q] + bb[q], h[q], d[q]);
                union { unsigned u[2]; bf16x4 v; } hb;
                hb.u[0] = packtr(h[0], h[1]);
                hb.u[1] = packtr(h[2], h[3]);
                cp = mfma16(nt ? w3f1 : w3f0, hb.v, cp);   // fz[i=4g+q][b=r], summed over 32 n
#pragma unroll
                for (int q = 0; q < 4; ++q) pp = fmaf(d[q], cv[nt][q], pp);   // d2 .* v, lane-local
            }
            *(f32x4*)&fzp[wv][r][4 * g] = cp;   // [b][i], i contiguous
            pp += __shfl_xor(pp, 16, 64);
            pp += __shfl_xor(pp, 32, 64);
            if (g == 0) divp[wv][r] = pp;
        }
        __syncthreads();   // B4: fzp ready (divp consumed next stage)

        if (wv == 0) {
            // ---------- z-update (wave 0): sum 8 fz partials + b3, RK4, packed zb write ----
            __builtin_amdgcn_s_setprio(1);
            f32x4 fa = {0.f, 0.f, 0.f, 0.f}, fb = {0.f, 0.f, 0.f, 0.f};
#pragma unroll
            for (int w = 0; w < 8; w += 2) {
                fa += *(const f32x4*)&fzp[w][r][4 * g];
                fb += *(const f32x4*)&fzp[w + 1][r][4 * g];
            }
            const f32x4* bp3 = (const f32x4*)&b3l[4 * g];
            const f32x4 b3v = bp3[opq];                  // per-stage reload, not a register
            const float coef = (s == 2) ? dt : 0.5f * dt;
            float zn[4];
#pragma unroll
            for (int q = 0; q < 4; ++q) {
                const float fz = fa[q] + fb[q] + b3v[q];
                za4[q] = fmaf(wst, fz, za4[q]);
                if (s < 3) zn[q] = fmaf(coef, fz, zb4[q]);
                else { zb4[q] = fmaf(dt6, za4[q], zb4[q]); zn[q] = zb4[q]; za4[q] = 0.0f; }
            }
            u32x2 pz = { cvt_pk_bf16(zn[0], zn[1]), cvt_pk_bf16(zn[2], zn[3]) };
            *(u32x2*)&zb[r][(4 * g) ^ zsw] = pz;
            if (lane < TILE_B) {                 // publish t for next stage
                const int it1 = it + 1;
                const int s1 = it1 & 3;
                const float t1 = dt * (float)(it1 >> 2) + ((s1 == 0) ? 0.0f : (s1 == 3) ? dt : 0.5f * dt);
                zb[lane][16 ^ (((lane >> 3) & 1) << 3)] = f2bf(t1);
            }
            __builtin_amdgcn_s_setprio(0);
        }
        // (loop-top barrier covers zb, t-col, divp and fzp reuse)
    }

    // ---------- epilogue ----------
    __syncthreads();
    if (wv == 1 && lane < TILE_B) {   // flush last stage (s=3, weight 1) and publish logp
        float dv = 0.0f;
#pragma unroll
        for (int w = 0; w < 8; ++w) dv += divp[w][lane];
        lacc -= dv;
        logp = fmaf(dt6, lacc, logp);
        divp[0][lane] = logp;
    }
    __syncthreads();
    if (wv == 0) {
        float ss = zb4[0] * zb4[0] + zb4[1] * zb4[1] + zb4[2] * zb4[2] + zb4[3] * zb4[3];
        ss += __shfl_xor(ss, 16, 64);
        ss += __shfl_xor(ss, 32, 64);
        if (g == 0)
            out[b0 + r] = -0.5f * (ss + (float)DIM * 1.8378770664093453f) - divp[0][r];
    }
}

extern "C" void kernel_launch(void* const* d_in, const int* in_sizes, int n_in,
                              void* d_out, int out_size, void* d_ws, size_t ws_size,
                              hipStream_t stream) {
    (void)in_sizes; (void)n_in; (void)out_size; (void)ws_size;
    const float* x  = (const float*)d_in[0];
    const float* W1 = (const float*)d_in[1];
    const float* b1 = (const float*)d_in[2];
    const float* W2 = (const float*)d_in[3];
    const float* b2 = (const float*)d_in[4];
    const float* W3 = (const float*)d_in[5];
    const float* b3 = (const float*)d_in[6];
    unsigned char* w2f8 = (unsigned char*)d_ws;                // 64 KB
    unsigned char* mtf8 = w2f8 + HID * HID;                    // 64 KB

    cnf_setup<<<HID, HID, 0, stream>>>(W1, W2, W3, w2f8, mtf8);
    cnf_main<<<8192 / TILE_B, NTHR, 0, stream>>>(x, W1, b1, b2, b3, w2f8, mtf8, W3, (float*)d_out);
}

// Round 17
// 176.078 us; speedup vs baseline: 1.0601x; 1.0601x over previous
//
#include <hip/hip_runtime.h>

#define DIM 16
#define HID 256
#define NSTEPS 10
#define TILE_B 32
#define NTHR 1024
#define LSH 264      // bf16 LDS row stride (shorts) for w3t; fp8 tiles use 264-BYTE stride.
                     // R31 = RESTORE R29 (session best: 127.1-127.5 us main, absmax 0.25).
                     // R30's 2-blocks/CU experiment regressed (138 us): spills returned
                     // (WRITE_SIZE 32KB->12MB) and occupancy did NOT rise (~42% both ways) --
                     // the second block never bought overlap. R28's packed-f32 also regressed
                     // (pk ops are 2-pass on SIMD-32 + pair-marshaling around scalar exp/rcp).
                     // R29 profile: VALU 55% + MFMA 31% = 86% combined issue, zero spills,
                     // LDS bytes at the fp8 minimum, bank conflicts at the b64 multi-pass floor.
                     // Structure: 16 waves; P1 all-wave transposed (W1ext^T @ zext^T, b1/t folded
                     // as K-cols); P2 operand-swapped fp8 MFMA (C=[n][b], batch in lanes, breg as
                     // long long read in place); h-waves epilogue: silu -> d2f8 + in-register
                     // K=16 MFMA fz partials; v-waves: lane-local divergence dot via cvt_pk_f32_fp8;
                     // wave 0/1 RK4 z-update from fzp; wave 8 deferred logp pipeline.

typedef __attribute__((ext_vector_type(8))) short bf16x8;
typedef __attribute__((ext_vector_type(4))) short bf16x4;
typedef __attribute__((ext_vector_type(4))) float f32x4;
typedef __attribute__((ext_vector_type(2))) float f32x2;
typedef __attribute__((ext_vector_type(2))) unsigned int u32x2;

__device__ __forceinline__ unsigned short f2bf(float f) {
    unsigned u = __float_as_uint(f);
    u += 0x7fff + ((u >> 16) & 1);          // RNE
    return (unsigned short)(u >> 16);
}
__device__ __forceinline__ unsigned cvt_pk_bf16(float lo, float hi) {   // [bf16(hi):bf16(lo)], RNE
    unsigned r;
    asm("v_cvt_pk_bf16_f32 %0, %1, %2" : "=v"(r) : "v"(lo), "v"(hi));
    return r;
}
__device__ __forceinline__ unsigned packtr(float a, float b) {   // [bf16(b):bf16(a)], trunc
    return __builtin_amdgcn_perm(__float_as_uint(b), __float_as_uint(a), 0x07060302u);
}
__device__ __forceinline__ unsigned pk4_fp8(float a, float b, float c, float d) {
    int w = __builtin_amdgcn_cvt_pk_fp8_f32(a, b, 0, false);     // bytes 0,1
    w = __builtin_amdgcn_cvt_pk_fp8_f32(c, d, w, true);          // bytes 2,3
    return (unsigned)w;
}
__device__ __forceinline__ void silu_both(float x, float& h, float& d) {
    float s = __builtin_amdgcn_rcpf(1.0f + __expf(-x));
    h = x * s;
    d = fmaf(h, 1.0f - s, s);               // silu' = s + h*(1-s)
}

#if defined(__has_builtin) && __has_builtin(__builtin_amdgcn_mfma_f32_16x16x16bf16_1k)
__device__ __forceinline__ f32x4 mfma16(bf16x4 a, bf16x4 b, f32x4 c) {
    return __builtin_amdgcn_mfma_f32_16x16x16bf16_1k(a, b, c, 0, 0, 0);
}
#else
__device__ __forceinline__ f32x4 mfma16(bf16x4 a, bf16x4 b, f32x4 c) {
    asm volatile("s_nop 1\n\t"
                 "v_mfma_f32_16x16x16_bf16 %0, %1, %2, %0\n\t"
                 "s_nop 7\n\t"
                 "s_nop 7"
                 : "+v"(c) : "v"(a), "v"(b));
    return c;
}
#endif

// w2f8[n][j] = fp8(W2[j][n]);  mtf8[n][j] = fp8(M[j][n]), M[j][n] = W2[j][n]*sum_i W1[i][j]*W3[n][i]
__global__ void cnf_setup(const float* __restrict__ W1, const float* __restrict__ W2,
                          const float* __restrict__ W3,
                          unsigned char* __restrict__ w2f8, unsigned char* __restrict__ mtf8) {
    const int n = blockIdx.x;
    const int j = threadIdx.x;
    float g = 0.0f;
#pragma unroll
    for (int i = 0; i < DIM; ++i) g = fmaf(W1[i * HID + j], W3[n * DIM + i], g);
    const float w2 = W2[j * HID + n];
    w2f8[n * HID + j] = (unsigned char)(__builtin_amdgcn_cvt_pk_fp8_f32(w2, w2, 0, false) & 0xff);
    const float m = w2 * g;
    mtf8[n * HID + j] = (unsigned char)(__builtin_amdgcn_cvt_pk_fp8_f32(m, m, 0, false) & 0xff);
}

__global__ __launch_bounds__(NTHR, 4) void cnf_main(
    const float* __restrict__ x,
    const float* __restrict__ W1, const float* __restrict__ b1,
    const float* __restrict__ b2, const float* __restrict__ b3,
    const unsigned char* __restrict__ w2f8, const unsigned char* __restrict__ mtf8,
    const float* __restrict__ W3, float* __restrict__ out)
{
    __shared__ unsigned short zb[TILE_B][40];   // z-ext^T rows: 0..15 = z, 16 = t, 17 = 1.0, 18..31 = 0
                                                // physical col = logical col ^ (8*bit3(row))
    __shared__ unsigned short w1e[HID][40];     // W1ext^T rows n, cols k=0..31 (16=t-row, 17=b1, rest 0)
    __shared__ unsigned short w3t[DIM][LSH];    // w3t[i][n] = W3[n][i]
    __shared__ unsigned char  h1f8[TILE_B][264];// fp8 h1 [b][n], 264-B stride
    __shared__ unsigned char  d1f8[TILE_B][264];
    __shared__ unsigned char  d2f8[TILE_B][264];// fp8 d2 [b][n]
    __shared__ alignas(16) float fzp[8][2][16][20];  // fz partials [hwave][bt][b][i], stride 20
    __shared__ alignas(16) float divp[8][TILE_B];
    __shared__ alignas(16) float b2l[HID];
    __shared__ alignas(16) float b3l[DIM];

    const int tid  = (int)threadIdx.x;
    const int lane = tid & 63;
    const int wv   = tid >> 6;            // 0..15
    const int g    = lane >> 4;           // quad 0..3
    const int r    = lane & 15;
    const int g8   = g * 8;
    const int b0   = (int)blockIdx.x * TILE_B;
    const int zsw  = ((r >> 3) & 1) << 3; // zb swizzle (8-short granule)
    const int n0w  = (wv & 7) * 32;

    // ---- update-wave (0/1) z-state: lane (r,g) holds z[b=wv*16+r][i=4g+q], fp32 ----
    float zb4[4] = {0, 0, 0, 0}, za4[4] = {0, 0, 0, 0};
    if (wv < 2) {
        const f32x4 xv = *(const f32x4*)&x[(b0 + wv * 16 + r) * DIM + 4 * g];
#pragma unroll
        for (int q = 0; q < 4; ++q) zb4[q] = xv[q];
        u32x2 pz = { cvt_pk_bf16(zb4[0], zb4[1]), cvt_pk_bf16(zb4[2], zb4[3]) };
        *(u32x2*)&zb[wv * 16 + r][(4 * g) ^ zsw] = pz;
    }
    if (tid < TILE_B) {      // ext cols: t(=0 for stage 0), one, zeros
        const int zswi = ((tid >> 3) & 1) << 3;
#pragma unroll
        for (int c = 16; c < 32; ++c)
            zb[tid][c ^ zswi] = (c == 17) ? (unsigned short)0x3F80 : (unsigned short)0;
    }
    {                        // w1e[n][k]: W1ext^T (one-time build, all 1024 threads)
        const int n = tid >> 2, kh = (tid & 3) * 8;
#pragma unroll
        for (int e = 0; e < 8; ++e) {
            const int k = kh + e;
            float v = 0.0f;
            if (k < 17)       v = W1[k * HID + n];   // k=16 is the t-row of W1
            else if (k == 17) v = b1[n];
            w1e[n][k] = f2bf(v);
        }
    }
    if (tid < 512) {         // w3t[i][n] = W3[n][i]
        const int n = tid >> 5, k0 = (tid & 31) * 8;
#pragma unroll
        for (int j = 0; j < 8; ++j) w3t[n][k0 + j] = f2bf(W3[(k0 + j) * DIM + n]);
    }
    if (tid < HID) b2l[tid] = b2[tid];   // biases live in LDS, re-read per stage (R19)
    if (tid < DIM) b3l[tid] = b3[tid];

    __syncthreads();         // init tables ready: hoist the loop-invariant fragments (R27)
    const bf16x8 w1v = *(const bf16x8*)&w1e[wv * 16 + r][g8];
    bf16x4 w3fa = {0, 0, 0, 0}, w3fb = {0, 0, 0, 0};
    if (wv < 8) {
        w3fa = *(const bf16x4*)&w3t[r][n0w + 4 * g];
        w3fb = *(const bf16x4*)&w3t[r][n0w + 16 + 4 * g];
    }

    // ---- phase-2 operand fragments (fp8, 32 regs; long long -> MFMA reads them in place) ----
    long long breg[8][2];
    {
        const unsigned char* Bg = (wv < 8) ? w2f8 : mtf8;
#pragma unroll
        for (int k = 0; k < 8; ++k)
#pragma unroll
            for (int nt = 0; nt < 2; ++nt)
                breg[k][nt] = *(const long long*)(Bg + (n0w + nt * 16 + r) * HID + k * 32 + g8);
    }

    float lacc = 0.0f, logp = 0.0f;
    const float dt = 0.1f, dt6 = dt / 6.0f;

    for (int it = 0; it < NSTEPS * 4; ++it) {
        const int s = it & 3;
        const float wst = (s == 1 || s == 2) ? 2.0f : 1.0f;
        int opq = 0;
        asm volatile("" : "+v"(opq));    // opaque 0: blocks hoisting of per-stage bias reloads
        __syncthreads();   // B1: zb (z + t col), prev-stage divp/fzp ready

        // ---------- deferred logp update for the PREVIOUS stage (wave 8) ----------
        if (wv == 8 && lane < TILE_B && it) {
            const int ps = (it + 3) & 3;
            const float pw = (ps == 1 || ps == 2) ? 2.0f : 1.0f;
            float dv = 0.0f;
#pragma unroll
            for (int w = 0; w < 8; ++w) dv += divp[w][lane];
            lacc = fmaf(-pw, dv, lacc);
            if (ps == 3) { logp = fmaf(dt6, lacc, logp); lacc = 0.0f; }
        }

        // ---------- phase 1 (all 16 waves, transposed): pre1^T[n][b] = W1ext^T @ zext^T
        //            -> h1,d1 fp8, single b32 store each ----------
        {
            const bf16x8 bz0 = *(const bf16x8*)&zb[r][g8 ^ zsw];
            const bf16x8 bz1 = *(const bf16x8*)&zb[16 + r][g8 ^ zsw];
#pragma unroll
            for (int bt = 0; bt < 2; ++bt) {
                f32x4 c = {0.f, 0.f, 0.f, 0.f};
                c = __builtin_amdgcn_mfma_f32_16x16x32_bf16(w1v, bt ? bz1 : bz0, c, 0, 0, 0);
                float h[4], d[4];
#pragma unroll
                for (int q = 0; q < 4; ++q) silu_both(c[q], h[q], d[q]);
                const int row = bt * 16 + r;
                const int col = wv * 16 + 4 * g;           // byte col, dword-aligned
                *(unsigned*)&h1f8[row][col] = pk4_fp8(h[0], h[1], h[2], h[3]);
                *(unsigned*)&d1f8[row][col] = pk4_fp8(d[0], d[1], d[2], d[3]);
            }
        }
        __syncthreads();   // B2: h1/d1 ready

        // ---------- phase 2 (operand-swapped fp8 MFMA): C[n][b], batch in lanes.
        //            A = breg (W2^T / M^T rows, fp8), B = h1/d1 rows (b64 reads) ----------
        f32x4 cc[2][2];    // [nt][bt]; cc[nt][bt][q] = pre2[n0w+nt*16+4g+q][bt*16+r]
        {
            const unsigned char (*aT)[264] = (wv < 8) ? h1f8 : d1f8;
#pragma unroll
            for (int a = 0; a < 2; ++a)
#pragma unroll
                for (int b = 0; b < 2; ++b) cc[a][b] = (f32x4){0.f, 0.f, 0.f, 0.f};
            __builtin_amdgcn_s_setprio(1);
#pragma unroll
            for (int k = 0; k < 8; ++k) {
                long long af[2];
#pragma unroll
                for (int bt = 0; bt < 2; ++bt)
                    af[bt] = *(const long long*)&aT[bt * 16 + r][k * 32 + g8];
#pragma unroll
                for (int nt = 0; nt < 2; ++nt)
#pragma unroll
                    for (int bt = 0; bt < 2; ++bt)
                        cc[nt][bt] = __builtin_amdgcn_mfma_f32_16x16x32_fp8_fp8(breg[k][nt], af[bt], cc[nt][bt], 0, 0, 0);
            }
            __builtin_amdgcn_s_setprio(0);
        }
        // no barrier: d2f8/fzp are fresh buffers this interval
        if (wv < 8) {
            // ---------- h-wave epilogue: silu -> d2f8 (fp8 b32 store); h2 stays in registers
            //            and feeds the per-wave fz partial (K=16 MFMA, B = lane-local silu) ----
            const f32x4* bp20 = (const f32x4*)&b2l[n0w + 4 * g];
            const f32x4* bp21 = (const f32x4*)&b2l[n0w + 16 + 4 * g];
            const f32x4 bb0 = bp20[opq], bb1 = bp21[opq];   // per-stage reload, not registers
#pragma unroll
            for (int bt = 0; bt < 2; ++bt) {
                f32x4 cp = {0.f, 0.f, 0.f, 0.f};
#pragma unroll
                for (int nt = 0; nt < 2; ++nt) {
                    float h[4], d[4];
                    const f32x4 bb = nt ? bb1 : bb0;
#pragma unroll
                    for (int q = 0; q < 4; ++q) silu_both(cc[nt][bt][q] + bb[q], h[q], d[q]);
                    union { unsigned u[2]; bf16x4 v; } hb;
                    hb.u[0] = packtr(h[0], h[1]);
                    hb.u[1] = packtr(h[2], h[3]);
                    const int row = bt * 16 + r;
                    const int col = n0w + nt * 16 + 4 * g;  // byte col
                    *(unsigned*)&d2f8[row][col] = pk4_fp8(d[0], d[1], d[2], d[3]);
                    cp = mfma16(nt ? w3fb : w3fa, hb.v, cp);   // K=16 partial: fz[i=4g+q][b=r]
                }
                *(f32x4*)&fzp[wv][bt][r][4 * g] = cp;   // [b][i], i contiguous
            }
        }
        __syncthreads();   // B4: d2f8 + fzp ready

        if (wv < 2) {
            // ---------- z-update (waves 0/1): sum 8 fz partials + b3, RK4, packed zb write ----
            __builtin_amdgcn_s_setprio(1);
            f32x4 fa = {0.f, 0.f, 0.f, 0.f}, fb = {0.f, 0.f, 0.f, 0.f};
#pragma unroll
            for (int w = 0; w < 8; w += 2) {
                fa += *(const f32x4*)&fzp[w][wv][r][4 * g];
                fb += *(const f32x4*)&fzp[w + 1][wv][r][4 * g];
            }
            const f32x4* bp3 = (const f32x4*)&b3l[4 * g];
            const f32x4 b3v = bp3[opq];                  // per-stage reload, not a register
            const float coef = (s == 2) ? dt : 0.5f * dt;
            float zn[4];
#pragma unroll
            for (int q = 0; q < 4; ++q) {
                const float fz = fa[q] + fb[q] + b3v[q];
                za4[q] = fmaf(wst, fz, za4[q]);
                if (s < 3) zn[q] = fmaf(coef, fz, zb4[q]);
                else { zb4[q] = fmaf(dt6, za4[q], zb4[q]); zn[q] = zb4[q]; za4[q] = 0.0f; }
            }
            u32x2 pz = { cvt_pk_bf16(zn[0], zn[1]), cvt_pk_bf16(zn[2], zn[3]) };
            *(u32x2*)&zb[wv * 16 + r][(4 * g) ^ zsw] = pz;
            if (wv == 0 && lane < TILE_B) {      // publish t for next stage
                const int it1 = it + 1;
                const int s1 = it1 & 3;
                const float t1 = dt * (float)(it1 >> 2) + ((s1 == 0) ? 0.0f : (s1 == 3) ? dt : 0.5f * dt);
                zb[lane][16 ^ (((lane >> 3) & 1) << 3)] = f2bf(t1);
            }
            __builtin_amdgcn_s_setprio(0);
        } else if (wv >= 8) {
            // ---------- v-waves: div_b = sum_n d2[b][n]*v[n][b]; batch lane-local.
            //            4 b32 reads + 8 cvt_pk + 16 fma + 4 shfl ----------
            float p0 = 0.0f, p1 = 0.0f;
#pragma unroll
            for (int nt = 0; nt < 2; ++nt)
#pragma unroll
                for (int bt = 0; bt < 2; ++bt) {
                    const int row = bt * 16 + r;
                    const int col = n0w + nt * 16 + 4 * g;
                    const unsigned du = *(const unsigned*)&d2f8[row][col];
                    const f32x2 lo = __builtin_amdgcn_cvt_pk_f32_fp8(du, false);
                    const f32x2 hi = __builtin_amdgcn_cvt_pk_f32_fp8(du, true);
                    float pp = (bt == 0) ? p0 : p1;
                    pp = fmaf(lo[0], cc[nt][bt][0], pp);
                    pp = fmaf(lo[1], cc[nt][bt][1], pp);
                    pp = fmaf(hi[0], cc[nt][bt][2], pp);
                    pp = fmaf(hi[1], cc[nt][bt][3], pp);
                    if (bt == 0) p0 = pp; else p1 = pp;
                }
            p0 += __shfl_xor(p0, 16, 64);
            p0 += __shfl_xor(p0, 32, 64);
            p1 += __shfl_xor(p1, 16, 64);
            p1 += __shfl_xor(p1, 32, 64);
            if (g < 2) divp[wv - 8][g * 16 + r] = g ? p1 : p0;
        }
        // (loop-top barrier covers zb, t-col, divp and fzp reuse)
    }

    // ---------- epilogue ----------
    __syncthreads();
    if (wv == 8 && lane < TILE_B) {   // flush last stage (s=3, weight 1) and publish logp
        float dv = 0.0f;
#pragma unroll
        for (int w = 0; w < 8; ++w) dv += divp[w][lane];
        lacc -= dv;
        logp = fmaf(dt6, lacc, logp);
        divp[0][lane] = logp;
    }
    __syncthreads();
    if (wv < 2) {
        float ss = zb4[0] * zb4[0] + zb4[1] * zb4[1] + zb4[2] * zb4[2] + zb4[3] * zb4[3];
        ss += __shfl_xor(ss, 16, 64);
        ss += __shfl_xor(ss, 32, 64);
        if (g == 0) {
            const int row = wv * 16 + r;
            out[b0 + row] = -0.5f * (ss + (float)DIM * 1.8378770664093453f) - divp[0][row];
        }
    }
}

extern "C" void kernel_launch(void* const* d_in, const int* in_sizes, int n_in,
                              void* d_out, int out_size, void* d_ws, size_t ws_size,
                              hipStream_t stream) {
    (void)in_sizes; (void)n_in; (void)out_size; (void)ws_size;
    const float* x  = (const float*)d_in[0];
    const float* W1 = (const float*)d_in[1];
    const float* b1 = (const float*)d_in[2];
    const float* W2 = (const float*)d_in[3];
    const float* b2 = (const float*)d_in[4];
    const float* W3 = (const float*)d_in[5];
    const float* b3 = (const float*)d_in[6];
    unsigned char* w2f8 = (unsigned char*)d_ws;                // 64 KB
    unsigned char* mtf8 = w2f8 + HID * HID;                    // 64 KB

    cnf_setup<<<HID, HID, 0, stream>>>(W1, W2, W3, w2f8, mtf8);
    cnf_main<<<8192 / TILE_B, NTHR, 0, stream>>>(x, W1, b1, b2, b3, w2f8, mtf8, W3, (float*)d_out);
}